// Round 13
// baseline (1424.683 us; speedup 1.0000x reference)
//
#include <hip/hip_runtime.h>

// ---------------- problem constants ----------------
#define T_TOK 8192          // B*S tokens
#define HID   2048
#define FFN_D 4096
#define NEXP  8
#define BM    128           // down-GEMM M tile
#define CAP_ROWS (T_TOK*2 + 256)         // 16640
#define MAX_TILES (T_TOK*2/BM + NEXP)    // 136 = 17*8
#define MAX_T2    (T_TOK*2/256 + NEXP)   // 72 (up 8-phase BM=256 tiles)
#define NB_8P   (32*MAX_T2)              // 2304 up GEMM blocks
#define CVT8P   16384                    // fused w2-cvt blocks (512 thr x 8 elems)
#define RT_BLKS  2048                    // route blocks in fused front launch
#define FCVT_BLKS 10240                  // w1/w3 cvt tail blocks in front launch
#define NB_DN   (32*MAX_TILES)           // 4352 down blocks (16 N x 2 Kz per tile)
#define PROWS   16384                    // rows per part plane
#define NTK 32                           // up K-tiles of 64 (HID/64)
#define NIT (NTK/2)                      // 16 iterations (2 K-tiles each)

typedef unsigned short u16;
typedef unsigned int   u32;
typedef __attribute__((ext_vector_type(8))) u16    u16x8;
typedef __attribute__((ext_vector_type(8))) __bf16 bf16x8;
typedef __attribute__((ext_vector_type(4))) __bf16 bf16x4;
typedef __attribute__((ext_vector_type(4))) float  f32x4;

// meta[] int layout inside ws
#define M_CNT 0
#define M_CUR 8
#define M_OFF 16
#define M_NT  24
#define M_NT2 25
#define M_TEXP 32      // [136]
#define M_TM0  192     // [136]
#define M_TEXP2 400    // [72]
#define M_TM02  480    // [72]

__device__ __forceinline__ u16 f2bf(float f){   // RNE f32 -> bf16
  u32 u = __float_as_uint(f);
  u += 0x7FFFu + ((u >> 16) & 1u);
  return (u16)(u >> 16);
}
__device__ __forceinline__ float bf2f(u16 v){
  return __uint_as_float(((u32)v) << 16);
}

__device__ __forceinline__ void gload16(const void* g, void* l){
  __builtin_amdgcn_global_load_lds((const __attribute__((address_space(1))) u32*)g,
                                   (__attribute__((address_space(3))) u32*)l, 16, 0, 0);
}

__device__ __forceinline__ bf16x8 cvt8(float4 v0, float4 v1){
  bf16x8 o;
  o[0]=(__bf16)v0.x; o[1]=(__bf16)v0.y; o[2]=(__bf16)v0.z; o[3]=(__bf16)v0.w;
  o[4]=(__bf16)v1.x; o[5]=(__bf16)v1.y; o[6]=(__bf16)v1.z; o[7]=(__bf16)v1.w;
  return o;
}

// ---------------- f32 -> bf16 stream convert (w2 fallback only) ----------------
__global__ __launch_bounds__(256) void moe_cvt(const float* __restrict__ src,
                                               u16* __restrict__ dst){
  size_t i = ((size_t)blockIdx.x * 256 + threadIdx.x) * 8;
  float4 v0 = *(const float4*)(src + i);
  float4 v1 = *(const float4*)(src + i + 4);
  *(bf16x8*)(dst + i) = cvt8(v0, v1);
}

// ---------------- fused front: routing + x->bf16 + w1/w3->bf16 ----------------
__global__ __launch_bounds__(256) void moe_route(const float* __restrict__ x,
                                                 const float* __restrict__ gw,
                                                 int* __restrict__ meta,
                                                 int* __restrict__ tok_top,
                                                 float* __restrict__ tok_wt,
                                                 u16* __restrict__ xb,
                                                 const float* __restrict__ w1,
                                                 u16* __restrict__ w1b,
                                                 const float* __restrict__ w3,
                                                 u16* __restrict__ w3b){
  if (blockIdx.x >= RT_BLKS){
    const size_t NELEM = (size_t)NEXP * FFN_D * HID;
    const size_t STR   = (size_t)FCVT_BLKS * 256 * 8;
    size_t i = ((size_t)(blockIdx.x - RT_BLKS) * 256 + threadIdx.x) * 8;
    for (; i < NELEM; i += STR){
      float4 a0 = *(const float4*)(w1 + i);
      float4 a1 = *(const float4*)(w1 + i + 4);
      *(bf16x8*)(w1b + i) = cvt8(a0, a1);
      float4 b0 = *(const float4*)(w3 + i);
      float4 b1 = *(const float4*)(w3 + i + 4);
      *(bf16x8*)(w3b + i) = cvt8(b0, b1);
    }
    return;
  }

  const int wid  = threadIdx.x >> 6;
  const int lane = threadIdx.x & 63;
  const int tok  = blockIdx.x * 4 + wid;
  const float* xr = x  + (size_t)tok * HID;
  u16*         xw = xb + (size_t)tok * HID;

  float s[NEXP];
  #pragma unroll
  for (int e=0;e<NEXP;e++) s[e]=0.f;

  for (int k = lane*4; k < HID; k += 256){
    const float4 xv = *(const float4*)(xr + k);
    bf16x4 xo;
    xo[0]=(__bf16)xv.x; xo[1]=(__bf16)xv.y; xo[2]=(__bf16)xv.z; xo[3]=(__bf16)xv.w;
    *(bf16x4*)(xw + k) = xo;
    #pragma unroll
    for (int e=0;e<NEXP;e++){
      const float4 g = *(const float4*)(gw + e*HID + k);
      s[e] += xv.x*g.x + xv.y*g.y + xv.z*g.z + xv.w*g.w;
    }
  }
  #pragma unroll
  for (int o=32;o;o>>=1){
    #pragma unroll
    for (int e=0;e<NEXP;e++) s[e] += __shfl_xor(s[e], o);
  }
  if (lane==0){
    float m1 = s[0]; int a = 0;
    #pragma unroll
    for (int e=1;e<NEXP;e++) if (s[e] > m1){ m1 = s[e]; a = e; }
    float m2 = -3.0e38f; int b = 0;
    #pragma unroll
    for (int e=0;e<NEXP;e++) if (e != a && s[e] > m2){ m2 = s[e]; b = e; }
    const float r  = __expf(m2 - m1);
    const float wa = 1.f / (1.f + r);
    tok_top[tok*2]   = a;  tok_top[tok*2+1] = b;
    tok_wt[tok*2]    = wa; tok_wt[tok*2+1]  = r * wa;
    atomicAdd(&meta[M_CNT + a], 1);
    atomicAdd(&meta[M_CNT + b], 1);
  }
}

// ---------------- prefix + both tile tables ----------------
__global__ void moe_prefix(int* __restrict__ meta){
  if (threadIdx.x != 0 || blockIdx.x != 0) return;
  int off = 0, nt = 0, nt2 = 0;
  for (int e=0;e<NEXP;e++){
    const int c = meta[M_CNT + e];
    meta[M_OFF + e] = off;
    meta[M_CUR + e] = off;
    const int ntE = (c + BM - 1) / BM;
    for (int i=0;i<ntE;i++){ meta[M_TEXP + nt] = e; meta[M_TM0 + nt] = off + i*BM; nt++; }
    const int ntE2 = (c + 255) / 256;
    for (int i=0;i<ntE2;i++){ meta[M_TEXP2 + nt2] = e; meta[M_TM02 + nt2] = off + i*256; nt2++; }
    off += c;
  }
  meta[M_NT]  = nt;
  meta[M_NT2] = nt2;
}

// ---------------- scatter (records pos_of aliased on tok_wt) ----------------
__global__ __launch_bounds__(256) void moe_scatter(const int* __restrict__ tok_top,
                                                   float* __restrict__ tok_wt,
                                                   int* __restrict__ meta,
                                                   int* __restrict__ row_tok,
                                                   float* __restrict__ row_w){
  const int i = blockIdx.x * 256 + threadIdx.x;
  const int e = tok_top[i];
  const float w = tok_wt[i];
  const int pos = atomicAdd(&meta[M_CUR + e], 1);
  row_tok[pos] = i >> 1;
  row_w[pos]   = w;
  ((int*)tok_wt)[i] = pos;
}

// ================= up-GEMM: 8-phase 256-tile template (m201 port) =================
// 512 thr, 8 waves (2M x 4N); per-wave 128 rows x (32 w1 + 32 w3) cols; BK=64.
// LDS: 2 bufs x 4 half-slots {A0,A1,B0,B1} each [128][64] bf16 = 128 KB.
// Tile T even -> buf0, odd -> buf1 (fixed). Per phase: reads | 1 half-tile stage |
// counted vmcnt at even phases | raw barrier | setprio(1) 16 MFMA setprio(0) | barrier.
// Each LDS slot is read ONCE per tile (frags reused in regs) and re-staged >=1
// barrier after its read. Swizzle: physical chunk = logical ^ (slotrow & 7).
#define SB0 __builtin_amdgcn_sched_barrier(0)
#define BARR __builtin_amdgcn_s_barrier()
#define VMW6 asm volatile("s_waitcnt vmcnt(6)" ::: "memory")
#define VMW0 asm volatile("s_waitcnt vmcnt(0)" ::: "memory")

#define SA(BF,H,KK) do{ \
    gload16(xb + aoff[H][0] + (KK), &L[BF][H][(0*512 + wid*64)*8]); \
    gload16(xb + aoff[H][1] + (KK), &L[BF][H][(1*512 + wid*64)*8]); }while(0)
#define SBm(BF,H,SRC,KK) do{ \
    gload16((SRC) + boff[0] + (KK), &L[BF][2+(H)][(0*512 + wid*64)*8]); \
    gload16((SRC) + boff[1] + (KK), &L[BF][2+(H)][(1*512 + wid*64)*8]); }while(0)
#define RA(BF,MH) do{ _Pragma("unroll") \
  for (int m3=0;m3<4;m3++){ _Pragma("unroll") for (int ks=0;ks<2;ks++){ \
    const int s_ = wm*64 + m3*16 + lr, c_ = ks*4 + lq; \
    af[m3][ks] = *(const bf16x8*)&L[BF][MH][s_*64 + ((c_ ^ (s_&7))*8)]; }}}while(0)
#define RB(BF,H,BB) do{ _Pragma("unroll") \
  for (int ni=0;ni<2;ni++){ _Pragma("unroll") for (int ks=0;ks<2;ks++){ \
    const int s_ = wn*32 + ni*16 + lr, c_ = ks*4 + lq; \
    BB[ni][ks] = *(const bf16x8*)&L[BF][2+(H)][s_*64 + ((c_ ^ (s_&7))*8)]; }}}while(0)
#define MMQ(MH,BH,BB) do{ __builtin_amdgcn_s_setprio(1); _Pragma("unroll") \
  for (int m3=0;m3<4;m3++){ _Pragma("unroll") for (int ni=0;ni<2;ni++){ \
    _Pragma("unroll") for (int ks=0;ks<2;ks++){ \
      acc[(MH)*4+m3][(BH)*2+ni] = __builtin_amdgcn_mfma_f32_16x16x32_bf16( \
        af[m3][ks], BB[ni][ks], acc[(MH)*4+m3][(BH)*2+ni],0,0,0); }}} \
  __builtin_amdgcn_s_setprio(0); }while(0)

__global__ __launch_bounds__(512,2) void moe_up_8p(
    const u16* __restrict__ xb, const u16* __restrict__ w1b, const u16* __restrict__ w3b,
    u16* __restrict__ act, const int* __restrict__ meta,
    const int* __restrict__ row_tok, const float* __restrict__ row_w,
    const float* __restrict__ w2, u16* __restrict__ w2b){
  if (blockIdx.x >= NB_8P){
    const size_t base = ((size_t)(blockIdx.x - NB_8P)) * 4096 + (size_t)threadIdx.x * 8;
    float4 v0 = *(const float4*)(w2 + base);
    float4 v1 = *(const float4*)(w2 + base + 4);
    *(bf16x8*)(w2b + base) = cvt8(v0, v1);
    return;
  }
  const int b    = blockIdx.x;
  const int xcd  = b & 7;
  const int q    = b >> 3;
  const int tile = q >> 2;
  const int n0   = (xcd + 8*(q & 3)) * 128;     // w1/w3 col base
  if (tile >= meta[M_NT2]) return;
  const int e      = meta[M_TEXP2 + tile];
  const int m0     = meta[M_TM02 + tile];
  const int rowEnd = meta[M_OFF + e] + meta[M_CNT + e];

  __shared__ u16 L[2][4][8192];   // 128 KB

  const int t = threadIdx.x, lane = t & 63, wid = t >> 6;
  const int wm = wid >> 2, wn = wid & 3;
  const int lr = lane & 15, lq = lane >> 4;

  const size_t eW = (size_t)e * FFN_D * HID;
  const u16* w1e = w1b + eW;
  const u16* w3e = w3b + eW;

  // staging offsets: 2 chunks/thread per half-slot
  u32 aoff[2][2], boff[2];
  #pragma unroll
  for (int i=0;i<2;i++){
    const int g = i*512 + t, s = g >> 3, pc = g & 7;
    const u32 sw = (u32)((pc ^ (s & 7)) * 8);
    const int band = s >> 6, srow = s & 63;
    aoff[0][i] = (u32)row_tok[m0 + band*128 +      srow] * HID + sw;
    aoff[1][i] = (u32)row_tok[m0 + band*128 + 64 + srow] * HID + sw;
    boff[i]    = (u32)(n0 + s) * HID + sw;
  }

  f32x4 acc[8][4];
  #pragma unroll
  for (int i=0;i<8;i++){
    #pragma unroll
    for (int j=0;j<4;j++) acc[i][j]=(f32x4)0.f;
  }
  bf16x8 af[4][2], bg[2][2], bu[2][2];

  // prologue: tiles 0 (buf0) and 1 (buf1); order defines vmcnt age
  SA(0,0,0); SBm(0,0,w1e,0); SBm(0,1,w3e,0); SA(0,1,0);
  SA(1,0,64); SBm(1,0,w1e,64); SBm(1,1,w3e,64); SA(1,1,64);
  asm volatile("s_waitcnt vmcnt(8)" ::: "memory");
  BARR;

  for (int i=0;i<NIT;i++){
    const int T = 2*i;
    const int k1 = (T+1)*64, k2 = (T+2)*64, k3 = (T+3)*64;
    const bool v1 = (T+1 >= 2);
    const bool v2 = (T+2 < NTK);
    const bool v3 = (T+3 < NTK);
    const bool tail = (i == NIT-1);
    // ph1: Q00 of T
    SB0; RA(0,0); RB(0,0,bg); if(v1) SBm(1,1,w3e,k1);
    BARR; SB0; MMQ(0,0,bg); BARR;
    // ph2: Q01 of T
    SB0; RB(0,1,bu); if(v1) SA(1,1,k1); if(tail){VMW0;}else{VMW6;}
    BARR; SB0; MMQ(0,1,bu); BARR;
    // ph3: Q10 of T
    SB0; RA(0,1); if(v2) SA(0,0,k2);
    BARR; SB0; MMQ(1,0,bg); BARR;
    // ph4: Q11 of T
    SB0; if(v2) SBm(0,0,w1e,k2); if(tail){VMW0;}else{VMW6;}
    BARR; SB0; MMQ(1,1,bu); BARR;
    // ph5: Q00 of T+1
    SB0; RA(1,0); RB(1,0,bg); if(v2) SBm(0,1,w3e,k2);
    BARR; SB0; MMQ(0,0,bg); BARR;
    // ph6: Q01 of T+1
    SB0; RB(1,1,bu); if(v2) SA(0,1,k2); if(tail){VMW0;}else{VMW6;}
    BARR; SB0; MMQ(0,1,bu); BARR;
    // ph7: Q10 of T+1
    SB0; RA(1,1); if(v3) SA(1,0,k3);
    BARR; SB0; MMQ(1,0,bg); BARR;
    // ph8: Q11 of T+1
    SB0; if(v3) SBm(1,0,w1e,k3); if(!tail){VMW6;}
    BARR; SB0; MMQ(1,1,bu); BARR;
  }

  // epilogue: act[pos][col] = bf16(relu(G)*U*rw); G=acc[mi][ci], U=acc[mi][ci+2]
  const int l4 = lq * 4;
  #pragma unroll
  for (int mi=0;mi<8;mi++){
    const int rowb = wm*128 + (mi>>2)*64 + (mi&3)*16 + l4;
    #pragma unroll
    for (int r=0;r<4;r++){
      const int pos = m0 + rowb + r;
      if (pos < rowEnd){
        const float rw = row_w[pos];
        #pragma unroll
        for (int ci=0;ci<2;ci++){
          const int col = n0 + wn*32 + ci*16 + lr;
          const float g = acc[mi][ci][r];
          const float u = acc[mi][ci+2][r];
          act[(size_t)pos * FFN_D + col] = f2bf(fmaxf(g, 0.f) * u * rw);
        }
      }
    }
  }
}

// ================= down-GEMM (proven 128x128) + XCD swizzle + K-split x2 =================
__global__ __launch_bounds__(256,2) void moe_down_f(
    const u16* __restrict__ act, const u16* __restrict__ w2b,
    u16* __restrict__ part, const int* __restrict__ meta){
  const int b    = blockIdx.x;
  const int q    = b >> 3;
  const int h    = q & 1;
  const int kz   = (q >> 1) & 1;
  const int tile = q >> 2;
  const int n0   = ((b & 7) + 8*h) * 128;
  if (tile >= meta[M_NT]) return;
  const int e      = meta[M_TEXP + tile];
  const int m0     = meta[M_TM0 + tile];
  const int rowEnd = meta[M_OFF + e] + meta[M_CNT + e];

  __shared__ u16 As[128*64];   // 16 KB
  __shared__ u16 Bs[128*64];   // 16 KB

  const int t    = threadIdx.x;
  const int lane = t & 63;
  const int wid  = t >> 6;
  const int wm   = wid >> 1, wn = wid & 1;
  const int lr = lane & 15;
  const int lq = lane >> 4;

  u32 aoff[4], boff[4];
  const u16* w2e = w2b + (size_t)e * HID * FFN_D;
  #pragma unroll
  for (int i=0;i<4;i++){
    const int g  = i*256 + t;
    const int r  = g >> 3;           // 0..127
    const int pc = g & 7;
    const int c8 = (pc ^ (r & 7)) * 8;
    aoff[i] = (u32)(m0 + r) * FFN_D + (u32)c8;
    boff[i] = (u32)(n0 + r) * FFN_D + (u32)c8;
  }

  f32x4 acc[4][4];
  #pragma unroll
  for (int i=0;i<4;i++){
    #pragma unroll
    for (int j=0;j<4;j++) acc[i][j]=(f32x4)0.f;
  }

  const int k0 = kz * (FFN_D/2);
  for (int kk = k0; kk < k0 + FFN_D/2; kk += 64){
    __syncthreads();
    #pragma unroll
    for (int i=0;i<4;i++)
      gload16(act + aoff[i] + kk, As + (size_t)(i*256 + wid*64)*8);
    #pragma unroll
    for (int i=0;i<4;i++)
      gload16(w2e + boff[i] + kk, Bs + (size_t)(i*256 + wid*64)*8);
    __syncthreads();

    #pragma unroll
    for (int ks=0; ks<2; ks++){
      const int c = ks*4 + lq;
      bf16x8 a[4], bb[4];
      #pragma unroll
      for (int mi=0;mi<4;mi++){
        const int r = wm*64 + mi*16 + lr;
        a[mi] = *(const bf16x8*)(As + r*64 + (c ^ (r&7))*8);
      }
      #pragma unroll
      for (int ni=0;ni<4;ni++){
        const int r = wn*64 + ni*16 + lr;
        bb[ni] = *(const bf16x8*)(Bs + r*64 + (c ^ (r&7))*8);
      }
      #pragma unroll
      for (int mi=0;mi<4;mi++){
        #pragma unroll
        for (int ni=0;ni<4;ni++)
          acc[mi][ni] = __builtin_amdgcn_mfma_f32_16x16x32_bf16(a[mi], bb[ni], acc[mi][ni],0,0,0);
      }
    }
  }

  const int l4 = lq * 4;
  u16* pbase = part + (size_t)kz * PROWS * HID;
  #pragma unroll
  for (int mi=0;mi<4;mi++){
    #pragma unroll
    for (int r=0;r<4;r++){
      const int pos = m0 + wm*64 + mi*16 + l4 + r;
      if (pos < rowEnd){
        u16* prow = pbase + (size_t)pos * HID;
        #pragma unroll
        for (int ni=0;ni<4;ni++){
          const int n = n0 + wn*64 + ni*16 + lr;
          prow[n] = f2bf(acc[mi][ni][r]);
        }
      }
    }
  }
}

// ---------------- combine: out[tok] = sum of 4 bf16 partials ----------------
__global__ __launch_bounds__(256) void moe_combine(const u16* __restrict__ part,
                                                   const int* __restrict__ pos_of,
                                                   float* __restrict__ out){
  const int tok = blockIdx.x;
  const int p0 = pos_of[tok*2];
  const int p1 = pos_of[tok*2+1];
  const int h = threadIdx.x * 8;
  const u16x8 a0 = *(const u16x8*)(part + ((size_t)p0)            * HID + h);
  const u16x8 a1 = *(const u16x8*)(part + ((size_t)PROWS + p0)    * HID + h);
  const u16x8 b0 = *(const u16x8*)(part + ((size_t)p1)            * HID + h);
  const u16x8 b1 = *(const u16x8*)(part + ((size_t)PROWS + p1)    * HID + h);
  float4 o0, o1;
  o0.x = (bf2f(a0[0])+bf2f(a1[0])) + (bf2f(b0[0])+bf2f(b1[0]));
  o0.y = (bf2f(a0[1])+bf2f(a1[1])) + (bf2f(b0[1])+bf2f(b1[1]));
  o0.z = (bf2f(a0[2])+bf2f(a1[2])) + (bf2f(b0[2])+bf2f(b1[2]));
  o0.w = (bf2f(a0[3])+bf2f(a1[3])) + (bf2f(b0[3])+bf2f(b1[3]));
  o1.x = (bf2f(a0[4])+bf2f(a1[4])) + (bf2f(b0[4])+bf2f(b1[4]));
  o1.y = (bf2f(a0[5])+bf2f(a1[5])) + (bf2f(b0[5])+bf2f(b1[5]));
  o1.z = (bf2f(a0[6])+bf2f(a1[6])) + (bf2f(b0[6])+bf2f(b1[6]));
  o1.w = (bf2f(a0[7])+bf2f(a1[7])) + (bf2f(b0[7])+bf2f(b1[7]));
  float* orow = out + (size_t)tok * HID + h;
  *(float4*)orow = o0;
  *(float4*)(orow + 4) = o1;
}

// ---------------- host ----------------
extern "C" void kernel_launch(void* const* d_in, const int* in_sizes, int n_in,
                              void* d_out, int out_size, void* d_ws, size_t ws_size,
                              hipStream_t stream) {
  const float* x  = (const float*)d_in[0];
  const float* gw = (const float*)d_in[1];
  const float* w1 = (const float*)d_in[2];
  const float* w2 = (const float*)d_in[3];
  const float* w3 = (const float*)d_in[4];
  float* out = (float*)d_out;

  const size_t OFF_ROWTOK = 4096;
  const size_t OFF_ROWW   = OFF_ROWTOK + (size_t)CAP_ROWS*4;
  const size_t OFF_TOP    = OFF_ROWW  + (size_t)CAP_ROWS*4;
  const size_t OFF_TOKW   = OFF_TOP   + (size_t)T_TOK*2*4;
  const size_t OFF_XB     = OFF_TOKW  + (size_t)T_TOK*2*4;
  const size_t XB_BYTES   = (size_t)T_TOK*HID*2;                  // 33.55 MB
  const size_t WB       = (size_t)NEXP*FFN_D*HID*2;               // 134.2 MB
  const size_t OFF_W1B  = OFF_XB  + XB_BYTES;
  const size_t OFF_W3B  = OFF_W1B + WB;       // part (2 planes) aliases after up
  const size_t OFF_ACTF = OFF_W3B + WB;
  const size_t ACT_BYTES= (size_t)CAP_ROWS*FFN_D*2;               // 136.3 MB
  const size_t WS_FAST  = OFF_ACTF + ACT_BYTES;                   // ~438.8 MB
  const size_t OFF_W2B  = OFF_ACTF + ACT_BYTES;
  const size_t WS_XL    = OFF_W2B + WB;                           // ~573 MB
  if (ws_size < WS_FAST) return;
  const bool xl = (ws_size >= WS_XL);

  char* ws = (char*)d_ws;
  int*   meta    = (int*)ws;
  int*   row_tok = (int*)(ws + OFF_ROWTOK);
  float* row_w   = (float*)(ws + OFF_ROWW);
  int*   tok_top = (int*)(ws + OFF_TOP);
  float* tok_wt  = (float*)(ws + OFF_TOKW);   // pos_of aliases this after scatter
  u16*   xb      = (u16*)(ws + OFF_XB);
  u16*   w1b     = (u16*)(ws + OFF_W1B);
  u16*   w3b     = (u16*)(ws + OFF_W3B);
  u16*   act     = (u16*)(ws + OFF_ACTF);
  u16*   part    = w3b;                        // w3b dead after up; needs exactly WB bytes
  u16*   w2b     = xl ? (u16*)(ws + OFF_W2B) : w1b;

  hipMemsetAsync(d_ws, 0, OFF_TOP, stream);   // meta + row_tok + row_w

  moe_route  <<<dim3(RT_BLKS + FCVT_BLKS), 256, 0, stream>>>(
      x, gw, meta, tok_top, tok_wt, xb, w1, w1b, w3, w3b);
  moe_prefix <<<1, 1, 0, stream>>>(meta);
  moe_scatter<<<dim3(T_TOK*2/256),    256, 0, stream>>>(tok_top, tok_wt, meta, row_tok, row_w);

  if (xl){
    moe_up_8p<<<dim3(NB_8P + CVT8P), 512, 0, stream>>>(
        xb, w1b, w3b, act, meta, row_tok, row_w, w2, w2b);
  } else {
    moe_up_8p<<<dim3(NB_8P), 512, 0, stream>>>(
        xb, w1b, w3b, act, meta, row_tok, row_w, w2, w2b);
    moe_cvt <<<dim3(32768), 256, 0, stream>>>(w2, w1b);
  }

  moe_down_f<<<dim3(NB_DN), 256, 0, stream>>>(act, w2b, part, meta);
  moe_combine<<<dim3(T_TOK), 256, 0, stream>>>(part, (const int*)tok_wt, out);
}

// Round 15
// 1269.430 us; speedup vs baseline: 1.1223x; 1.1223x over previous
//
#include <hip/hip_runtime.h>

// ---------------- problem constants ----------------
#define T_TOK 8192          // B*S tokens
#define HID   2048
#define FFN_D 4096
#define NEXP  8
#define BM    128           // GEMM M tile (both GEMMs)
#define CAP_ROWS (T_TOK*2 + 256)         // 16640
#define MAX_TILES (T_TOK*2/BM + NEXP)    // 136 = 17*8
#define NB_UP   (64*MAX_TILES)           // 8704 GEMM blocks in up launch
#define CVT_BLKS 32768                   // fused w2-cvt blocks in up launch
#define RT_BLKS  2048                    // route blocks in fused front launch
#define FCVT_BLKS 10240                  // w1/w3 cvt tail blocks in front launch
#define NB_DN   (32*MAX_TILES)           // 4352 down blocks (16 N x 2 Kz per tile)
#define PROWS   16384                    // rows per part plane (pos < 16384 always)

typedef unsigned short u16;
typedef unsigned int   u32;
typedef __attribute__((ext_vector_type(8))) u16    u16x8;
typedef __attribute__((ext_vector_type(8))) __bf16 bf16x8;
typedef __attribute__((ext_vector_type(4))) __bf16 bf16x4;
typedef __attribute__((ext_vector_type(4))) float  f32x4;

// meta[] int layout inside ws
#define M_CNT 0
#define M_CUR 8
#define M_OFF 16
#define M_NT  24
#define M_TEXP 32      // [136]
#define M_TM0  192     // [136]

__device__ __forceinline__ u16 f2bf(float f){   // RNE f32 -> bf16
  u32 u = __float_as_uint(f);
  u += 0x7FFFu + ((u >> 16) & 1u);
  return (u16)(u >> 16);
}
__device__ __forceinline__ float bf2f(u16 v){
  return __uint_as_float(((u32)v) << 16);
}

__device__ __forceinline__ void gload16(const void* g, void* l){
  __builtin_amdgcn_global_load_lds((const __attribute__((address_space(1))) u32*)g,
                                   (__attribute__((address_space(3))) u32*)l, 16, 0, 0);
}

__device__ __forceinline__ bf16x8 cvt8(float4 v0, float4 v1){
  bf16x8 o;
  o[0]=(__bf16)v0.x; o[1]=(__bf16)v0.y; o[2]=(__bf16)v0.z; o[3]=(__bf16)v0.w;
  o[4]=(__bf16)v1.x; o[5]=(__bf16)v1.y; o[6]=(__bf16)v1.z; o[7]=(__bf16)v1.w;
  return o;
}

// ---------------- f32 -> bf16 stream convert (w2 fallback only) ----------------
__global__ __launch_bounds__(256) void moe_cvt(const float* __restrict__ src,
                                               u16* __restrict__ dst){
  size_t i = ((size_t)blockIdx.x * 256 + threadIdx.x) * 8;
  float4 v0 = *(const float4*)(src + i);
  float4 v1 = *(const float4*)(src + i + 4);
  *(bf16x8*)(dst + i) = cvt8(v0, v1);
}

// ---------------- fused front: routing + x->bf16 + w1/w3->bf16 ----------------
// blocks [0, RT_BLKS): one wave per token (4 tokens/block); also writes xb.
// blocks [RT_BLKS, RT_BLKS+FCVT_BLKS): grid-stride convert of w1 and w3.
__global__ __launch_bounds__(256) void moe_route(const float* __restrict__ x,
                                                 const float* __restrict__ gw,
                                                 int* __restrict__ meta,
                                                 int* __restrict__ tok_top,
                                                 float* __restrict__ tok_wt,
                                                 u16* __restrict__ xb,
                                                 const float* __restrict__ w1,
                                                 u16* __restrict__ w1b,
                                                 const float* __restrict__ w3,
                                                 u16* __restrict__ w3b){
  if (blockIdx.x >= RT_BLKS){
    const size_t NELEM = (size_t)NEXP * FFN_D * HID;            // 67,108,864 per weight
    const size_t STR   = (size_t)FCVT_BLKS * 256 * 8;           // 20,971,520
    size_t i = ((size_t)(blockIdx.x - RT_BLKS) * 256 + threadIdx.x) * 8;
    for (; i < NELEM; i += STR){
      float4 a0 = *(const float4*)(w1 + i);
      float4 a1 = *(const float4*)(w1 + i + 4);
      *(bf16x8*)(w1b + i) = cvt8(a0, a1);
      float4 b0 = *(const float4*)(w3 + i);
      float4 b1 = *(const float4*)(w3 + i + 4);
      *(bf16x8*)(w3b + i) = cvt8(b0, b1);
    }
    return;
  }

  const int wid  = threadIdx.x >> 6;
  const int lane = threadIdx.x & 63;
  const int tok  = blockIdx.x * 4 + wid;
  const float* xr = x  + (size_t)tok * HID;
  u16*         xw = xb + (size_t)tok * HID;

  float s[NEXP];
  #pragma unroll
  for (int e=0;e<NEXP;e++) s[e]=0.f;

  for (int k = lane*4; k < HID; k += 256){
    const float4 xv = *(const float4*)(xr + k);
    bf16x4 xo;
    xo[0]=(__bf16)xv.x; xo[1]=(__bf16)xv.y; xo[2]=(__bf16)xv.z; xo[3]=(__bf16)xv.w;
    *(bf16x4*)(xw + k) = xo;
    #pragma unroll
    for (int e=0;e<NEXP;e++){
      const float4 g = *(const float4*)(gw + e*HID + k);
      s[e] += xv.x*g.x + xv.y*g.y + xv.z*g.z + xv.w*g.w;
    }
  }
  #pragma unroll
  for (int o=32;o;o>>=1){
    #pragma unroll
    for (int e=0;e<NEXP;e++) s[e] += __shfl_xor(s[e], o);
  }
  if (lane==0){
    float m1 = s[0]; int a = 0;
    #pragma unroll
    for (int e=1;e<NEXP;e++) if (s[e] > m1){ m1 = s[e]; a = e; }
    float m2 = -3.0e38f; int b = 0;
    #pragma unroll
    for (int e=0;e<NEXP;e++) if (e != a && s[e] > m2){ m2 = s[e]; b = e; }
    const float r  = __expf(m2 - m1);
    const float wa = 1.f / (1.f + r);
    tok_top[tok*2]   = a;  tok_top[tok*2+1] = b;
    tok_wt[tok*2]    = wa; tok_wt[tok*2+1]  = r * wa;
    atomicAdd(&meta[M_CNT + a], 1);
    atomicAdd(&meta[M_CNT + b], 1);
  }
}

// ---------------- prefix + tile table ----------------
__global__ void moe_prefix(int* __restrict__ meta){
  if (threadIdx.x != 0 || blockIdx.x != 0) return;
  int off = 0, nt = 0;
  for (int e=0;e<NEXP;e++){
    const int c = meta[M_CNT + e];
    meta[M_OFF + e] = off;
    meta[M_CUR + e] = off;
    const int ntE = (c + BM - 1) / BM;
    for (int i=0;i<ntE;i++){ meta[M_TEXP + nt] = e; meta[M_TM0 + nt] = off + i*BM; nt++; }
    off += c;
  }
  meta[M_NT] = nt;
}

// ---------------- scatter (pos_of now in a DEDICATED buffer; no aliasing) ----------------
__global__ __launch_bounds__(256) void moe_scatter(const int* __restrict__ tok_top,
                                                   const float* __restrict__ tok_wt,
                                                   int* __restrict__ meta,
                                                   int* __restrict__ row_tok,
                                                   float* __restrict__ row_w,
                                                   int* __restrict__ pos_of){
  const int i = blockIdx.x * 256 + threadIdx.x;
  const int e = tok_top[i];
  const float w = tok_wt[i];
  const int pos = atomicAdd(&meta[M_CUR + e], 1);
  row_tok[pos] = i >> 1;
  row_w[pos]   = w;
  pos_of[i]    = pos;
}

// ================= up-GEMM (proven structure) + XCD swizzle + fused w2 cvt =================
// 1-D grid. GEMM blocks b < NB_UP: tile=(b>>3)>>3, n=(b&7)+8*((b>>3)&7).
// XCD k owns N-columns n===k (mod 8): its 8 B-panels (4 MB) stay L2-resident across M-tiles.
// LDS: [rows][64] bf16 in 16B chunks; logical chunk c of row r at pc = c ^ (r&7).
__global__ __launch_bounds__(256,2) void moe_up_f(
    const u16* __restrict__ xb, const u16* __restrict__ w1b, const u16* __restrict__ w3b,
    u16* __restrict__ act, const int* __restrict__ meta,
    const int* __restrict__ row_tok, const float* __restrict__ row_w,
    const float* __restrict__ w2, u16* __restrict__ w2b){
  if (blockIdx.x >= NB_UP){
    const size_t base = ((size_t)(blockIdx.x - NB_UP)) * 2048 + (size_t)threadIdx.x * 8;
    float4 v0 = *(const float4*)(w2 + base);
    float4 v1 = *(const float4*)(w2 + base + 4);
    *(bf16x8*)(w2b + base) = cvt8(v0, v1);
    return;
  }
  const int b    = blockIdx.x;
  const int q    = b >> 3;
  const int tile = q >> 3;                 // 0..135
  const int n0   = ((b & 7) + 8*(q & 7)) * 64;
  if (tile >= meta[M_NT]) return;
  const int e      = meta[M_TEXP + tile];
  const int m0     = meta[M_TM0 + tile];
  const int rowEnd = meta[M_OFF + e] + meta[M_CNT + e];

  __shared__ u16 As[128*64];     // 16 KB
  __shared__ u16 Bs[2*64*64];    // 16 KB (w1 | w3)

  const int t    = threadIdx.x;
  const int lane = t & 63;
  const int wid  = t >> 6;
  const int wm   = wid >> 1, wn = wid & 1;
  const int lr = lane & 15;
  const int lq = lane >> 4;

  u32 aoff[4], boff[4];
  #pragma unroll
  for (int i=0;i<4;i++){
    const int g  = i*256 + t;        // chunk id 0..1023
    const int r  = g >> 3;           // 0..127
    const int pc = g & 7;
    aoff[i] = (u32)row_tok[m0 + r] * HID + (u32)((pc ^ (r & 7)) * 8);
    const int rr = r & 63;
    boff[i] = (u32)(n0 + rr) * HID + (u32)((pc ^ (rr & 7)) * 8);
  }
  const size_t eW = (size_t)e * FFN_D * HID;
  const u16* w1e = w1b + eW;
  const u16* w3e = w3b + eW;

  f32x4 accG[4][2], accU[4][2];
  #pragma unroll
  for (int i=0;i<4;i++){
    #pragma unroll
    for (int j=0;j<2;j++){ accG[i][j]=(f32x4)0.f; accU[i][j]=(f32x4)0.f; }
  }

  for (int kk = 0; kk < HID; kk += 64){
    __syncthreads();
    #pragma unroll
    for (int i=0;i<4;i++)
      gload16(xb + aoff[i] + kk, As + (size_t)(i*256 + wid*64)*8);
    gload16(w1e + boff[0] + kk, Bs + (size_t)(0*256 + wid*64)*8);
    gload16(w1e + boff[1] + kk, Bs + (size_t)(1*256 + wid*64)*8);
    gload16(w3e + boff[2] + kk, Bs + (size_t)(2*256 + wid*64)*8);
    gload16(w3e + boff[3] + kk, Bs + (size_t)(3*256 + wid*64)*8);
    __syncthreads();

    #pragma unroll
    for (int ks=0; ks<2; ks++){
      const int c = ks*4 + lq;
      bf16x8 a[4], bG[2], bU[2];
      #pragma unroll
      for (int mi=0;mi<4;mi++){
        const int r = wm*64 + mi*16 + lr;
        a[mi] = *(const bf16x8*)(As + r*64 + (c ^ (r&7))*8);
      }
      #pragma unroll
      for (int ni=0;ni<2;ni++){
        const int r  = wn*32 + ni*16 + lr;
        const int po = (c ^ (r&7))*8;
        bG[ni] = *(const bf16x8*)(Bs + r*64 + po);
        bU[ni] = *(const bf16x8*)(Bs + 4096 + r*64 + po);
      }
      #pragma unroll
      for (int mi=0;mi<4;mi++){
        #pragma unroll
        for (int ni=0;ni<2;ni++){
          accG[mi][ni] = __builtin_amdgcn_mfma_f32_16x16x32_bf16(a[mi], bG[ni], accG[mi][ni],0,0,0);
          accU[mi][ni] = __builtin_amdgcn_mfma_f32_16x16x32_bf16(a[mi], bU[ni], accU[mi][ni],0,0,0);
        }
      }
    }
  }

  const int l4 = lq * 4;
  #pragma unroll
  for (int mi=0;mi<4;mi++){
    #pragma unroll
    for (int r=0;r<4;r++){
      const int pos = m0 + wm*64 + mi*16 + l4 + r;
      if (pos < rowEnd){
        const float rw = row_w[pos];
        #pragma unroll
        for (int ni=0;ni<2;ni++){
          const int n = n0 + wn*32 + ni*16 + lr;
          const float g = accG[mi][ni][r];
          const float u = accU[mi][ni][r];
          act[(size_t)pos * FFN_D + n] = f2bf(fmaxf(g, 0.f) * u * rw);
        }
      }
    }
  }
}

// ================= down-GEMM (proven 128x128) + XCD swizzle + K-split x2 =================
// 1-D grid of 32*136=4352. Decode: r=b&7 (XCD), q=b>>3: h=q&1 (N-half), kz=(q>>1)&1
// (K-half), tile=q>>2. A-row reads clamped to <PROWS so padding tiles never touch
// unwritten memory (outputs for those rows are guard-discarded anyway).
__global__ __launch_bounds__(256,2) void moe_down_f(
    const u16* __restrict__ act, const u16* __restrict__ w2b,
    u16* __restrict__ part, const int* __restrict__ meta){
  const int b    = blockIdx.x;
  const int q    = b >> 3;
  const int h    = q & 1;
  const int kz   = (q >> 1) & 1;
  const int tile = q >> 2;
  const int n0   = ((b & 7) + 8*h) * 128;
  if (tile >= meta[M_NT]) return;
  const int e      = meta[M_TEXP + tile];
  const int m0     = meta[M_TM0 + tile];
  const int rowEnd = meta[M_OFF + e] + meta[M_CNT + e];

  __shared__ u16 As[128*64];   // 16 KB
  __shared__ u16 Bs[128*64];   // 16 KB

  const int t    = threadIdx.x;
  const int lane = t & 63;
  const int wid  = t >> 6;
  const int wm   = wid >> 1, wn = wid & 1;
  const int lr = lane & 15;
  const int lq = lane >> 4;

  u32 aoff[4], boff[4];
  const u16* w2e = w2b + (size_t)e * HID * FFN_D;
  #pragma unroll
  for (int i=0;i<4;i++){
    const int g  = i*256 + t;
    const int r  = g >> 3;           // 0..127
    const int pc = g & 7;
    const int c8 = (pc ^ (r & 7)) * 8;
    int ar = m0 + r;
    if (ar > PROWS-1) ar = PROWS-1;  // clamp: never read unwritten act rows
    aoff[i] = (u32)ar * FFN_D + (u32)c8;
    boff[i] = (u32)(n0 + r) * FFN_D + (u32)c8;
  }

  f32x4 acc[4][4];
  #pragma unroll
  for (int i=0;i<4;i++){
    #pragma unroll
    for (int j=0;j<4;j++) acc[i][j]=(f32x4)0.f;
  }

  const int k0 = kz * (FFN_D/2);
  for (int kk = k0; kk < k0 + FFN_D/2; kk += 64){
    __syncthreads();
    #pragma unroll
    for (int i=0;i<4;i++)
      gload16(act + aoff[i] + kk, As + (size_t)(i*256 + wid*64)*8);
    #pragma unroll
    for (int i=0;i<4;i++)
      gload16(w2e + boff[i] + kk, Bs + (size_t)(i*256 + wid*64)*8);
    __syncthreads();

    #pragma unroll
    for (int ks=0; ks<2; ks++){
      const int c = ks*4 + lq;
      bf16x8 a[4], bb[4];
      #pragma unroll
      for (int mi=0;mi<4;mi++){
        const int r = wm*64 + mi*16 + lr;
        a[mi] = *(const bf16x8*)(As + r*64 + (c ^ (r&7))*8);
      }
      #pragma unroll
      for (int ni=0;ni<4;ni++){
        const int r = wn*64 + ni*16 + lr;
        bb[ni] = *(const bf16x8*)(Bs + r*64 + (c ^ (r&7))*8);
      }
      #pragma unroll
      for (int mi=0;mi<4;mi++){
        #pragma unroll
        for (int ni=0;ni<4;ni++)
          acc[mi][ni] = __builtin_amdgcn_mfma_f32_16x16x32_bf16(a[mi], bb[ni], acc[mi][ni],0,0,0);
      }
    }
  }

  const int l4 = lq * 4;
  u16* pbase = part + (size_t)kz * PROWS * HID;
  #pragma unroll
  for (int mi=0;mi<4;mi++){
    #pragma unroll
    for (int r=0;r<4;r++){
      const int pos = m0 + wm*64 + mi*16 + l4 + r;
      if (pos < rowEnd){
        u16* prow = pbase + (size_t)pos * HID;
        #pragma unroll
        for (int ni=0;ni<4;ni++){
          const int n = n0 + wn*64 + ni*16 + lr;
          prow[n] = f2bf(acc[mi][ni][r]);
        }
      }
    }
  }
}

// ---------------- combine: out[tok] = sum of 4 bf16 partials (2 pos x 2 K-halves) ----------------
__global__ __launch_bounds__(256) void moe_combine(const u16* __restrict__ part,
                                                   const int* __restrict__ pos_of,
                                                   float* __restrict__ out){
  const int tok = blockIdx.x;
  const int p0 = pos_of[tok*2];
  const int p1 = pos_of[tok*2+1];
  const int h = threadIdx.x * 8;
  const u16x8 a0 = *(const u16x8*)(part + ((size_t)p0)            * HID + h);
  const u16x8 a1 = *(const u16x8*)(part + ((size_t)PROWS + p0)    * HID + h);
  const u16x8 b0 = *(const u16x8*)(part + ((size_t)p1)            * HID + h);
  const u16x8 b1 = *(const u16x8*)(part + ((size_t)PROWS + p1)    * HID + h);
  float4 o0, o1;
  o0.x = (bf2f(a0[0])+bf2f(a1[0])) + (bf2f(b0[0])+bf2f(b1[0]));
  o0.y = (bf2f(a0[1])+bf2f(a1[1])) + (bf2f(b0[1])+bf2f(b1[1]));
  o0.z = (bf2f(a0[2])+bf2f(a1[2])) + (bf2f(b0[2])+bf2f(b1[2]));
  o0.w = (bf2f(a0[3])+bf2f(a1[3])) + (bf2f(b0[3])+bf2f(b1[3]));
  o1.x = (bf2f(a0[4])+bf2f(a1[4])) + (bf2f(b0[4])+bf2f(b1[4]));
  o1.y = (bf2f(a0[5])+bf2f(a1[5])) + (bf2f(b0[5])+bf2f(b1[5]));
  o1.z = (bf2f(a0[6])+bf2f(a1[6])) + (bf2f(b0[6])+bf2f(b1[6]));
  o1.w = (bf2f(a0[7])+bf2f(a1[7])) + (bf2f(b0[7])+bf2f(b1[7]));
  float* orow = out + (size_t)tok * HID + h;
  *(float4*)orow = o0;
  *(float4*)(orow + 4) = o1;
}

// ---------------- host ----------------
extern "C" void kernel_launch(void* const* d_in, const int* in_sizes, int n_in,
                              void* d_out, int out_size, void* d_ws, size_t ws_size,
                              hipStream_t stream) {
  const float* x  = (const float*)d_in[0];
  const float* gw = (const float*)d_in[1];
  const float* w1 = (const float*)d_in[2];
  const float* w2 = (const float*)d_in[3];
  const float* w3 = (const float*)d_in[4];
  float* out = (float*)d_out;

  const size_t OFF_ROWTOK = 4096;
  const size_t OFF_ROWW   = OFF_ROWTOK + (size_t)CAP_ROWS*4;
  const size_t OFF_TOP    = OFF_ROWW  + (size_t)CAP_ROWS*4;
  const size_t OFF_TOKW   = OFF_TOP   + (size_t)T_TOK*2*4;
  const size_t OFF_POS    = OFF_TOKW  + (size_t)T_TOK*2*4;        // dedicated pos_of
  const size_t OFF_XB     = OFF_POS   + (size_t)T_TOK*2*4;
  const size_t XB_BYTES   = (size_t)T_TOK*HID*2;                  // 33.55 MB
  const size_t WB       = (size_t)NEXP*FFN_D*HID*2;               // 134.2 MB
  const size_t OFF_W1B  = OFF_XB  + XB_BYTES;
  const size_t OFF_W3B  = OFF_W1B + WB;       // part (2 x 16384 x 2048 bf16 = WB) aliases after up
  const size_t OFF_ACTF = OFF_W3B + WB;
  const size_t ACT_BYTES= (size_t)CAP_ROWS*FFN_D*2;               // 136.3 MB
  const size_t WS_FAST  = OFF_ACTF + ACT_BYTES;                   // ~438.9 MB
  const size_t OFF_W2B  = OFF_ACTF + ACT_BYTES;
  const size_t WS_XL    = OFF_W2B + WB;                           // ~573 MB
  if (ws_size < WS_FAST) return;
  const bool xl = (ws_size >= WS_XL);

  char* ws = (char*)d_ws;
  int*   meta    = (int*)ws;
  int*   row_tok = (int*)(ws + OFF_ROWTOK);
  float* row_w   = (float*)(ws + OFF_ROWW);
  int*   tok_top = (int*)(ws + OFF_TOP);
  float* tok_wt  = (float*)(ws + OFF_TOKW);
  int*   pos_of  = (int*)(ws + OFF_POS);
  u16*   xb      = (u16*)(ws + OFF_XB);
  u16*   w1b     = (u16*)(ws + OFF_W1B);
  u16*   w3b     = (u16*)(ws + OFF_W3B);
  u16*   act     = (u16*)(ws + OFF_ACTF);
  u16*   part    = w3b;                        // w3b dead after up; needs exactly WB bytes
  u16*   w2b     = xl ? (u16*)(ws + OFF_W2B) : w1b;  // separate slot only in XL

  hipMemsetAsync(d_ws, 0, OFF_TOP, stream);   // meta + row_tok + row_w

  // fused front: routing + x->bf16 + w1/w3->bf16 (one launch)
  moe_route  <<<dim3(RT_BLKS + FCVT_BLKS), 256, 0, stream>>>(
      x, gw, meta, tok_top, tok_wt, xb, w1, w1b, w3, w3b);
  moe_prefix <<<1, 1, 0, stream>>>(meta);
  moe_scatter<<<dim3(T_TOK*2/256),    256, 0, stream>>>(tok_top, tok_wt, meta, row_tok, row_w, pos_of);

  if (xl){
    // w2 cvt rides inside the up launch (tail blocks past NB_UP)
    moe_up_f<<<dim3(NB_UP + CVT_BLKS), 256, 0, stream>>>(
        xb, w1b, w3b, act, meta, row_tok, row_w, w2, w2b);
  } else {
    moe_up_f<<<dim3(NB_UP), 256, 0, stream>>>(
        xb, w1b, w3b, act, meta, row_tok, row_w, w2, w2b);
    moe_cvt <<<dim3(32768), 256, 0, stream>>>(w2, w1b);   // sequential fallback
  }

  moe_down_f<<<dim3(NB_DN), 256, 0, stream>>>(act, w2b, part, meta);
  moe_combine<<<dim3(T_TOK), 256, 0, stream>>>(part, pos_of, out);
}